// Round 7
// baseline (76.894 us; speedup 1.0000x reference)
//
#include <hip/hip_runtime.h>
#include <math.h>

#define DD     768
#define NPIX   50176          // 224*224
#define NPIX4  12544          // NPIX/4
#define NK     16             // K-chunks per matrix

typedef float f4 __attribute__((ext_vector_type(4)));

// ---- workspace layout (float offsets) ----
#define WS_PART 0                       // 4 mats * NK * 768 partials
#define WS_TBL  (4*NK*DD)               // 1538-entry channel-value table:
                                        // [0..767]=alpha*pos, [768]=sb,
                                        // [769..1536]=dec_vec, [1537]=ml
#define WS_SYNC (WS_TBL + 1544)         // 1 uint ticket counter (memset/call)

// ---- output layout (float offsets, tuple order concatenated) ----
// maps region O_SPM..O_ML+NPIX is one contiguous 1538*NPIX block
#define O_PROMPT 0
#define O_SP     (O_PROMPT + DD)
#define O_SPM    (O_SP + DD)
#define O_SB     (O_SPM + (size_t)DD*NPIX)
#define O_DEC    (O_SB + NPIX)
#define O_ML     (O_DEC + (size_t)DD*NPIX)
#define O_ALPHA  (O_ML + NPIX)
#define O_NL     (O_ALPHA + 1)

__device__ __forceinline__ float gelu_exact(float x) {
    return 0.5f * x * (1.0f + erff(x * 0.70710678118654752f));
}
__device__ __forceinline__ float sigmoidf(float x) {
    return 1.0f / (1.0f + expf(-x));
}

// K1: partial matvecs + last-block glue. grid=64, block=192.
// block b: matrix m = b>>4, K-chunk = b&15. Thread t covers cols 4t..4t+3.
// The block drawing ticket 63 (all partials released) performs the glue.
__global__ __launch_bounds__(192) void k_matvec_glue(
    const float* __restrict__ query, const float* __restrict__ pos,
    const float* __restrict__ neg,   const float* __restrict__ bnd,
    const float* __restrict__ alpha_w1, const float* __restrict__ alpha_b1,
    const float* __restrict__ alpha_w2, const float* __restrict__ alpha_b2,
    const float* __restrict__ neg_w1,   const float* __restrict__ neg_b1,
    const float* __restrict__ neg_w2,   const float* __restrict__ neg_b2,
    const float* __restrict__ prompt_w, const float* __restrict__ prompt_b,
    const float* __restrict__ dec_w,    const float* __restrict__ dec_b,
    const float* __restrict__ logit_w,  const float* __restrict__ logit_b,
    float* __restrict__ ws, float* __restrict__ out)
{
    const int b = blockIdx.x;
    const int t = threadIdx.x;
    const int m = b >> 4, kchunk = b & 15;
    const int j0 = 4 * t;

    const float* W = (m == 0) ? alpha_w1 : (m == 1) ? prompt_w
                   : (m == 2) ? dec_w    : neg_w1;

    __shared__ float xs[144];
    if (m == 3) {
        const int k0 = kchunk * 48;
        if (t < 48) xs[t] = neg[k0 + t];
    } else {
        const int k0 = kchunk * 144;
        if (t < 144) {
            int k = k0 + t;
            float v;
            if (k < DD)          v = pos[k];
            else if (k < 2 * DD) v = neg[k - DD];
            else                 v = bnd[k - 2 * DD];
            xs[t] = v;
        }
    }
    __syncthreads();

    f4 acc = {0.f, 0.f, 0.f, 0.f};
    if (m == 3) {
        const float* Wp = W + (size_t)(kchunk * 48) * DD + j0;
        #pragma unroll 16
        for (int kk = 0; kk < 48; ++kk)
            acc += xs[kk] * (*(const f4*)(Wp + (size_t)kk * DD));
    } else {
        const float* Wp = W + (size_t)(kchunk * 144) * DD + j0;
        #pragma unroll 16
        for (int kk = 0; kk < 144; ++kk)
            acc += xs[kk] * (*(const f4*)(Wp + (size_t)kk * DD));
    }
    *(f4*)(ws + WS_PART + (size_t)(m * NK + kchunk) * DD + j0) = acc;

    // ---- ticket: last block to finish does the glue (no spinning) ----
    __shared__ unsigned sh_old;
    __syncthreads();                              // drain all waves' stores
    if (t == 0) {
        __threadfence();                          // release partials
        sh_old = atomicAdd((unsigned*)(ws + WS_SYNC), 1u);
    }
    __syncthreads();
    if (sh_old != 63u) return;
    if (t == 0) __threadfence();                  // acquire others' partials
    __syncthreads();

    // ---- glue: 192 threads, f4 over 768 cols ----
    const float* P = ws + WS_PART;
    f4 ah = {0,0,0,0}, pr = {0,0,0,0}, dc = {0,0,0,0}, ng = {0,0,0,0};
    #pragma unroll
    for (int c = 0; c < NK; ++c) {
        ah += *(const f4*)(P + (size_t)(0 * NK + c) * DD + j0);
        pr += *(const f4*)(P + (size_t)(1 * NK + c) * DD + j0);
        dc += *(const f4*)(P + (size_t)(2 * NK + c) * DD + j0);
        ng += *(const f4*)(P + (size_t)(3 * NK + c) * DD + j0);
    }

    pr += *(const f4*)(prompt_b + j0);
    const f4 dec_v = dc + *(const f4*)(dec_b + j0);
    *(f4*)(out + O_PROMPT + j0) = pr;             // prompt_tokens
    #pragma unroll
    for (int u = 0; u < 4; ++u)                   // dec channel (odd offset)
        ws[WS_TBL + 769 + j0 + u] = dec_v[u];

    const f4 ab1  = *(const f4*)(alpha_b1 + j0);
    const f4 nb1  = *(const f4*)(neg_b1   + j0);
    const f4 aw2  = *(const f4*)(alpha_w2 + j0);
    const f4 nw2  = *(const f4*)(neg_w2   + j0);
    const f4 lw   = *(const f4*)(logit_w  + j0);
    const f4 negj = *(const f4*)(neg      + j0);
    const f4 bndj = *(const f4*)(bnd      + j0);
    float r0 = 0.f, r1 = 0.f, r2 = 0.f, r3 = 0.f, r4 = 0.f;
    #pragma unroll
    for (int u = 0; u < 4; ++u) {
        const float ga  = gelu_exact(ah[u] + ab1[u]);
        const float gn  = gelu_exact(ng[u] + nb1[u]);
        const float dbd = bndj[u] - negj[u];
        r0 += ga * aw2[u];
        r1 += gn * nw2[u];
        r2 += dec_v[u] * lw[u];
        r3 += negj[u] * lw[u];
        r4 += dbd * dbd;
    }
    #pragma unroll
    for (int s = 32; s > 0; s >>= 1) {
        r0 += __shfl_xor(r0, s, 64);
        r1 += __shfl_xor(r1, s, 64);
        r2 += __shfl_xor(r2, s, 64);
        r3 += __shfl_xor(r3, s, 64);
        r4 += __shfl_xor(r4, s, 64);
    }
    __shared__ float red[5][3];
    __shared__ float sh_alpha;
    const int wid = t >> 6;
    if ((t & 63) == 0) {
        red[0][wid] = r0; red[1][wid] = r1; red[2][wid] = r2;
        red[3][wid] = r3; red[4][wid] = r4;
    }
    __syncthreads();
    if (t == 0) {
        const float s0 = red[0][0] + red[0][1] + red[0][2];
        const float s1 = red[1][0] + red[1][1] + red[1][2];
        const float s2 = red[2][0] + red[2][1] + red[2][2];
        const float s3 = red[3][0] + red[3][1] + red[3][2];
        const float s4 = red[4][0] + red[4][1] + red[4][2];
        const float alpha = sigmoidf(s0 + alpha_b2[0]);
        const float nl    = sigmoidf(s1 + neg_b2[0]);
        const float ld    = s2 + logit_b[0];
        const float ln    = s3 + logit_b[0];
        out[O_ALPHA]      = alpha;
        out[O_NL]         = nl;
        ws[WS_TBL + 768]  = sqrtf(s4);            // sb
        ws[WS_TBL + 1537] = ld - nl * ln;         // ml
        sh_alpha = alpha;
    }
    __syncthreads();

    const float alpha = sh_alpha;
    const f4 ap = alpha * (*(const f4*)(pos + j0));
    *(f4*)(out + O_SP + j0) = ap + (1.0f - alpha) * (*(const f4*)(query + j0));
    #pragma unroll
    for (int u = 0; u < 4; ++u)
        ws[WS_TBL + j0 + u] = ap[u];              // spm channel values
}

// K3: flat broadcast fill of the 1538*NPIX contiguous map region.
// grid = 2048 blocks (8/CU, perfectly balanced), block = 256.
__global__ __launch_bounds__(256) void k_fill(
    const float* __restrict__ ws, float* __restrict__ out)
{
    const float* tbl = ws + WS_TBL;
    f4* p = (f4*)(out + O_SPM);
    const unsigned total  = 1538u * NPIX4;        // 19,292,672 float4s
    const unsigned stride = gridDim.x * 256u;
    for (unsigned i = blockIdx.x * 256u + threadIdx.x; i < total; i += stride) {
        const unsigned c = i / NPIX4;             // magic-mul divide
        const float v = tbl[c];
        f4 v4 = {v, v, v, v};
        __builtin_nontemporal_store(v4, p + i);
    }
}

extern "C" void kernel_launch(void* const* d_in, const int* in_sizes, int n_in,
                              void* d_out, int out_size, void* d_ws, size_t ws_size,
                              hipStream_t stream) {
    const float* query    = (const float*)d_in[0];
    const float* pos      = (const float*)d_in[1];
    const float* neg      = (const float*)d_in[2];
    const float* bnd      = (const float*)d_in[3];
    // d_in[4] = spatial_map: values never used (shape-only in reference)
    const float* alpha_w1 = (const float*)d_in[5];
    const float* alpha_b1 = (const float*)d_in[6];
    const float* alpha_w2 = (const float*)d_in[7];
    const float* alpha_b2 = (const float*)d_in[8];
    const float* neg_w1   = (const float*)d_in[9];
    const float* neg_b1   = (const float*)d_in[10];
    const float* neg_w2   = (const float*)d_in[11];
    const float* neg_b2   = (const float*)d_in[12];
    const float* prompt_w = (const float*)d_in[13];
    const float* prompt_b = (const float*)d_in[14];
    const float* dec_w    = (const float*)d_in[15];
    const float* dec_b    = (const float*)d_in[16];
    const float* logit_w  = (const float*)d_in[17];
    const float* logit_b  = (const float*)d_in[18];

    float* out = (float*)d_out;
    float* ws  = (float*)d_ws;

    // zero the 4-byte ticket counter — graph-capturable, deterministic
    hipMemsetAsync((char*)d_ws + (size_t)WS_SYNC * sizeof(float), 0,
                   sizeof(unsigned), stream);

    // K1: partial matvecs + last-block glue
    k_matvec_glue<<<64, 192, 0, stream>>>(
        query, pos, neg, bnd,
        alpha_w1, alpha_b1, alpha_w2, alpha_b2,
        neg_w1, neg_b1, neg_w2, neg_b2,
        prompt_w, prompt_b, dec_w, dec_b,
        logit_w, logit_b, ws, out);

    // K3: big broadcast fill (nontemporal, flat, balanced)
    k_fill<<<2048, 256, 0, stream>>>(ws, out);
}

// Round 8
// 74.897 us; speedup vs baseline: 1.0267x; 1.0267x over previous
//
#include <hip/hip_runtime.h>
#include <math.h>

#define DD     768
#define NPIX   50176          // 224*224
#define NPIX4  12544          // NPIX/4
#define NCH    160            // partial chunks total: 48+48+48+16

typedef float f4 __attribute__((ext_vector_type(4)));

// ---- workspace layout (float offsets) ----
#define WS_PART 0                       // NCH * 768 partials
#define WS_TBL  (NCH*DD)                // 1538-entry channel-value table:
                                        // [0..767]=alpha*pos, [768]=sb,
                                        // [769..1536]=dec_vec, [1537]=ml

// ---- output layout (float offsets, tuple order concatenated) ----
// maps region O_SPM..O_ML+NPIX is one contiguous 1538*NPIX block
#define O_PROMPT 0
#define O_SP     (O_PROMPT + DD)
#define O_SPM    (O_SP + DD)
#define O_SB     (O_SPM + (size_t)DD*NPIX)
#define O_DEC    (O_SB + NPIX)
#define O_ML     (O_DEC + (size_t)DD*NPIX)
#define O_ALPHA  (O_ML + NPIX)
#define O_NL     (O_ALPHA + 1)

__device__ __forceinline__ float gelu_exact(float x) {
    return 0.5f * x * (1.0f + erff(x * 0.70710678118654752f));
}
__device__ __forceinline__ float sigmoidf(float x) {
    return 1.0f / (1.0f + expf(-x));
}

// K1: partial matvecs, f4 weight loads, 48-row chunks. grid=160, block=192.
// blocks 0..143: m = b/48 (0=alpha_w1, 1=prompt_w, 2=dec_w), chunk c = b%48
// blocks 144..159: m = 3 (neg_w1), chunk c = b-144
// Thread t covers cols j0 = 4t .. 4t+3.
__global__ __launch_bounds__(192) void k_matvec_part(
    const float* __restrict__ pos, const float* __restrict__ neg,
    const float* __restrict__ bnd,
    const float* __restrict__ alpha_w1, const float* __restrict__ prompt_w,
    const float* __restrict__ dec_w,   const float* __restrict__ neg_w1,
    float* __restrict__ ws)
{
    const int b = blockIdx.x;
    const int t = threadIdx.x;
    int m, c;
    if (b < 144) { m = b / 48; c = b % 48; }
    else         { m = 3;      c = b - 144; }
    const float* W = (m == 0) ? alpha_w1 : (m == 1) ? prompt_w
                   : (m == 2) ? dec_w    : neg_w1;
    const int k0 = c * 48;

    __shared__ float xs[48];
    if (t < 48) {
        int k = k0 + t;
        float v;
        if (m == 3)           v = neg[k];
        else if (k < DD)      v = pos[k];
        else if (k < 2 * DD)  v = neg[k - DD];
        else                  v = bnd[k - 2 * DD];
        xs[t] = v;
    }
    __syncthreads();

    const int j0 = 4 * t;
    f4 acc = {0.f, 0.f, 0.f, 0.f};
    const float* Wp = W + (size_t)k0 * DD + j0;
    #pragma unroll 16
    for (int kk = 0; kk < 48; ++kk)
        acc += xs[kk] * (*(const f4*)(Wp + (size_t)kk * DD));

    *(f4*)(ws + WS_PART + (size_t)b * DD + j0) = acc;
}

// K2: one block of 768 threads (12 waves) — all scalar/vector glue.
// Partial layout: chunks [0,48)=ah, [48,96)=pr, [96,144)=dc, [144,160)=ng.
__global__ __launch_bounds__(768) void k_small(
    const float* __restrict__ query, const float* __restrict__ pos,
    const float* __restrict__ neg,   const float* __restrict__ bnd,
    const float* __restrict__ alpha_b1, const float* __restrict__ alpha_w2,
    const float* __restrict__ alpha_b2,
    const float* __restrict__ neg_b1,   const float* __restrict__ neg_w2,
    const float* __restrict__ neg_b2,
    const float* __restrict__ prompt_b, const float* __restrict__ dec_b,
    const float* __restrict__ logit_w,  const float* __restrict__ logit_b,
    float* __restrict__ ws, float* __restrict__ out)
{
    const int j = threadIdx.x;  // 0..767

    // reduce K-chunk partials (coalesced across threads, L2-hot)
    float a_h = 0.f, pr = 0.f, dc = 0.f, ng = 0.f;
    #pragma unroll 8
    for (int c = 0; c < 48; ++c) a_h += ws[WS_PART + (size_t)c * DD + j];
    #pragma unroll 8
    for (int c = 48; c < 96; ++c) pr += ws[WS_PART + (size_t)c * DD + j];
    #pragma unroll 8
    for (int c = 96; c < 144; ++c) dc += ws[WS_PART + (size_t)c * DD + j];
    #pragma unroll 8
    for (int c = 144; c < 160; ++c) ng += ws[WS_PART + (size_t)c * DD + j];

    pr += prompt_b[j];
    const float dec_v = dc + dec_b[j];
    out[O_PROMPT + j]       = pr;     // prompt_tokens
    ws[WS_TBL + 769 + j]    = dec_v;  // decoder map channel value

    const float ga   = gelu_exact(a_h + alpha_b1[j]);
    const float gn   = gelu_exact(ng  + neg_b1[j]);
    const float negj = neg[j];
    const float lw   = logit_w[j];
    const float dbd  = bnd[j] - negj;

    float r[5];
    r[0] = ga * alpha_w2[j];
    r[1] = gn * neg_w2[j];
    r[2] = dec_v * lw;
    r[3] = negj * lw;
    r[4] = dbd * dbd;

    // per-wave butterfly reduction (64 lanes)
    #pragma unroll
    for (int s = 32; s > 0; s >>= 1) {
        #pragma unroll
        for (int q = 0; q < 5; ++q) r[q] += __shfl_xor(r[q], s, 64);
    }

    __shared__ float red[5][12];
    const int wid = j >> 6, lane = j & 63;
    if (lane == 0) {
        #pragma unroll
        for (int q = 0; q < 5; ++q) red[q][wid] = r[q];
    }
    __syncthreads();

    __shared__ float sh_alpha;
    if (j == 0) {
        float s[5];
        #pragma unroll
        for (int q = 0; q < 5; ++q) {
            float tsum = 0.f;
            #pragma unroll
            for (int w = 0; w < 12; ++w) tsum += red[q][w];
            s[q] = tsum;
        }
        const float alpha = sigmoidf(s[0] + alpha_b2[0]);
        const float nl    = sigmoidf(s[1] + neg_b2[0]);
        const float ld    = s[2] + logit_b[0];
        const float ln    = s[3] + logit_b[0];
        out[O_ALPHA]       = alpha;
        out[O_NL]          = nl;
        ws[WS_TBL + 768]   = sqrtf(s[4]);      // sb
        ws[WS_TBL + 1537]  = ld - nl * ln;     // ml
        sh_alpha = alpha;
    }
    __syncthreads();

    const float alpha = sh_alpha;
    const float ap    = alpha * pos[j];
    out[O_SP + j]  = ap + (1.0f - alpha) * query[j];  // semantic_prototype
    ws[WS_TBL + j] = ap;                              // spm channel value
}

// K3: flat broadcast fill of the 1538*NPIX contiguous map region.
// grid = 2048 blocks (8/CU, perfectly balanced), block = 256.
__global__ __launch_bounds__(256) void k_fill(
    const float* __restrict__ ws, float* __restrict__ out)
{
    const float* tbl = ws + WS_TBL;
    f4* p = (f4*)(out + O_SPM);
    const unsigned total  = 1538u * NPIX4;        // 19,292,672 float4s
    const unsigned stride = gridDim.x * 256u;
    for (unsigned i = blockIdx.x * 256u + threadIdx.x; i < total; i += stride) {
        const unsigned c = i / NPIX4;             // magic-mul divide
        const float v = tbl[c];
        f4 v4 = {v, v, v, v};
        __builtin_nontemporal_store(v4, p + i);
    }
}

extern "C" void kernel_launch(void* const* d_in, const int* in_sizes, int n_in,
                              void* d_out, int out_size, void* d_ws, size_t ws_size,
                              hipStream_t stream) {
    const float* query    = (const float*)d_in[0];
    const float* pos      = (const float*)d_in[1];
    const float* neg      = (const float*)d_in[2];
    const float* bnd      = (const float*)d_in[3];
    // d_in[4] = spatial_map: values never used (shape-only in reference)
    const float* alpha_w1 = (const float*)d_in[5];
    const float* alpha_b1 = (const float*)d_in[6];
    const float* alpha_w2 = (const float*)d_in[7];
    const float* alpha_b2 = (const float*)d_in[8];
    const float* neg_w1   = (const float*)d_in[9];
    const float* neg_b1   = (const float*)d_in[10];
    const float* neg_w2   = (const float*)d_in[11];
    const float* neg_b2   = (const float*)d_in[12];
    const float* prompt_w = (const float*)d_in[13];
    const float* prompt_b = (const float*)d_in[14];
    const float* dec_w    = (const float*)d_in[15];
    const float* dec_b    = (const float*)d_in[16];
    const float* logit_w  = (const float*)d_in[17];
    const float* logit_b  = (const float*)d_in[18];

    float* out = (float*)d_out;
    float* ws  = (float*)d_ws;

    // K1: partial matvecs (f4 weight loads, 160 blocks)
    k_matvec_part<<<NCH, 192, 0, stream>>>(
        pos, neg, bnd, alpha_w1, prompt_w, dec_w, neg_w1, ws);

    // K2: reductions + scalar chain + small outputs + channel-value table
    k_small<<<1, DD, 0, stream>>>(
        query, pos, neg, bnd,
        alpha_b1, alpha_w2, alpha_b2,
        neg_b1, neg_w2, neg_b2,
        prompt_b, dec_b, logit_w, logit_b,
        ws, out);

    // K3: big broadcast fill (nontemporal, flat, balanced)
    k_fill<<<2048, 256, 0, stream>>>(ws, out);
}